// Round 8
// baseline (650.501 us; speedup 1.0000x reference)
//
#include <hip/hip_runtime.h>
#include <hip/hip_bf16.h>
#include <math.h>

#define B_    4
#define SEQ_  1024
#define E_    512
#define H_    8
#define DH_   64
#define NHYP_ 6
#define HID_  2048
#define NC_   6
#define ENC_  6
#define BH_   (B_*H_)
#define NCAT_ 1088   // 512 Q + 512 V + 48 proj + 16 pad

typedef __attribute__((ext_vector_type(8))) short short8;
typedef __attribute__((ext_vector_type(4))) float f32x4;

static __device__ __forceinline__ float wave_rsum(float v){
#pragma unroll
  for(int o=32;o;o>>=1) v += __shfl_down(v,o,64);
  return v;
}
static __device__ __forceinline__ ushort f2b(float v){
  __hip_bfloat16 h = __float2bfloat16(v);
  return *(ushort*)&h;
}
static __device__ __forceinline__ float b2f(ushort u){
  unsigned int x = ((unsigned int)u) << 16;
  return *(float*)&x;
}
// async global->LDS, 16B/lane; LDS dest = wave-uniform base + lane*16 (linear)
static __device__ __forceinline__ void gload16(const void* g, void* l){
  __builtin_amdgcn_global_load_lds(
      (const __attribute__((address_space(1))) void*)g,
      (__attribute__((address_space(3))) void*)l,
      16, 0, 0);
}

// x[b,s,:] = emb[idx[b,s],:] + pos_encoding(s,:)   (fp32 + bf16 copies)
__global__ void embed_pe_kernel(const int* __restrict__ inp, const float* __restrict__ emb,
                                float* __restrict__ x, ushort* __restrict__ xh){
  int row = blockIdx.x;            // b*SEQ + s
  int s = row & (SEQ_-1);
  int idx = inp[row];
  const float* er = emb + (size_t)idx*E_;
  float* xr = x + (size_t)row*E_;
  ushort* hr = xh + (size_t)row*E_;
  for(int c=threadIdx.x;c<E_;c+=blockDim.x){
    int i = c>>1;
    float div = expf(-(float)i * 0.0359778920780319646f);
    float ang = (float)s * div;
    float pe = (c&1) ? cosf(ang) : sinf(ang);
    float v = er[c] + pe;
    xr[c] = v;
    hr[c] = f2b(v);
  }
}

// one-time: W[K][N] fp32 -> Wt[N][K] bf16
__global__ __launch_bounds__(256) void transpose_cast(
    const float* __restrict__ W, ushort* __restrict__ Wt, int K, int N){
  __shared__ float T[32][33];
  int tx = threadIdx.x & 31, ty = threadIdx.x >> 5;   // 32x8
  int n0 = blockIdx.x*32, k0 = blockIdx.y*32;
#pragma unroll
  for(int i=0;i<32;i+=8) T[ty+i][tx] = W[(size_t)(k0+ty+i)*N + n0+tx];
  __syncthreads();
#pragma unroll
  for(int i=0;i<32;i+=8)
    Wt[(size_t)(n0+ty+i)*K + k0+tx] = f2b(T[tx][ty+i]);
}

// one-time: W_projT rows of WcatT. WcatT[1024+c][k] = sum_d Wq[k][h*64+d]*hyper[d*6+y]
__global__ void wproj_build(const float* __restrict__ Wq, const float* __restrict__ hyper,
                            ushort* __restrict__ WcatT){
  int t = blockIdx.x*256 + threadIdx.x;   // 64*512
  int c = t >> 9, k = t & 511;
  float s = 0.f;
  if(c < 48){
    int h = c/6, y = c%6;
    const float* wr = Wq + (size_t)k*E_ + h*DH_;
    for(int d=0;d<DH_;++d) s += wr[d]*hyper[d*NHYP_+y];
  }
  WcatT[(size_t)(1024+c)*E_ + k] = f2b(s);
}

// one-time: concatenated bias [bq | bv | bproj | 0]
__global__ void bias_build(const float* __restrict__ bq, const float* __restrict__ bv,
                           const float* __restrict__ hyper, float* __restrict__ bcat){
  int t = blockIdx.x*256 + threadIdx.x;
  if(t >= NCAT_) return;
  float v;
  if(t < 512) v = bq[t];
  else if(t < 1024) v = bv[t-512];
  else if(t < 1072){
    int c = t - 1024, h = c/6, y = c%6;
    float s = hyper[DH_*NHYP_ + y];
    for(int d=0;d<DH_;++d) s += bq[h*DH_+d]*hyper[d*NHYP_+y];
    v = s;
  } else v = 0.f;
  bcat[t] = v;
}

// C = A[M,K](bf16) @ Bt[N,K]^T(bf16) + bias.
// BK=64, swizzled LDS (XOR chunk^(row&7)), double-buffered, 1 barrier/K-step.
// EPI 0: fp32->C0. 1: relu->bf16 C0. 2: +res -> fp32 C0.
// 5: fused QVproj: cc<512 -> Qh=C1 (bf16 head layout); cc<1024 -> Vt=C2 (bf16
//    transposed); cc<1072 -> proj fp32 -> C0 (stride 64); else discard.
template<int BM, int BN, int EPI>
__global__ __launch_bounds__(256) void gemm_mfma(
    const ushort* __restrict__ A, const ushort* __restrict__ Bt,
    const float* __restrict__ bias, const float* __restrict__ res,
    void* __restrict__ C0, void* __restrict__ C1, void* __restrict__ C2,
    int M, int N, int K)
{
  constexpr int MI = BM/32, NI = BN/32;
  constexpr int ACH = BM/32, BCH = BN/32;   // gload iters (BM*8 chunks / 256 thr)
  __shared__ ushort As[2][BM*64];
  __shared__ ushort Bs[2][BN*64];
  int tid = threadIdx.x;
  int w = tid>>6, lane = tid&63, g = lane>>4, li = lane&15;
  int wr = w>>1, wc = w&1;
  int bm = blockIdx.y*BM, bn = blockIdx.x*BN;
  int NK = K>>6;

  f32x4 acc[MI][NI] = {};

  auto issue = [&](int ks, int pb){
    int k0 = ks*64;
#pragma unroll
    for(int it=0; it<ACH; ++it){
      int c = it*256 + tid; int r = c>>3; int kq = ((c&7)^(r&7))*8;
      gload16(&A[(size_t)(bm+r)*K + k0 + kq], &As[pb][it*2048 + w*512]);
    }
#pragma unroll
    for(int it=0; it<BCH; ++it){
      int c = it*256 + tid; int r = c>>3; int kq = ((c&7)^(r&7))*8;
      gload16(&Bt[(size_t)(bn+r)*K + k0 + kq], &Bs[pb][it*2048 + w*512]);
    }
  };

  issue(0, 0);
  __syncthreads();
  for(int ks=0; ks<NK; ++ks){
    if(ks+1 < NK) issue(ks+1, (ks+1)&1);
    int pb = ks&1;
#pragma unroll
    for(int kc=0; kc<2; ++kc){
      short8 af[MI], bf[NI];
#pragma unroll
      for(int mi=0;mi<MI;++mi)
        af[mi] = *(const short8*)&As[pb][(wr*(BM/2)+mi*16+li)*64 + (((kc*4+g)^(li&7))*8)];
#pragma unroll
      for(int ni=0;ni<NI;++ni)
        bf[ni] = *(const short8*)&Bs[pb][(wc*(BN/2)+ni*16+li)*64 + (((kc*4+g)^(li&7))*8)];
#pragma unroll
      for(int mi=0;mi<MI;++mi)
#pragma unroll
        for(int ni=0;ni<NI;++ni)
          acc[mi][ni] = __builtin_amdgcn_mfma_f32_16x16x32_bf16(af[mi], bf[ni], acc[mi][ni], 0,0,0);
    }
    __syncthreads();
  }

#pragma unroll
  for(int mi=0;mi<MI;++mi){
    int rbase = bm + wr*(BM/2) + mi*16 + g*4;
#pragma unroll
    for(int ni=0;ni<NI;++ni){
      int cc = bn + wc*(BN/2) + ni*16 + li;
      float bv = bias[cc];
      float vv[4];
#pragma unroll
      for(int j=0;j<4;++j) vv[j] = acc[mi][ni][j] + bv;
      if(EPI==0){
#pragma unroll
        for(int j=0;j<4;++j) ((float*)C0)[(size_t)(rbase+j)*N + cc] = vv[j];
      } else if(EPI==1){
#pragma unroll
        for(int j=0;j<4;++j) ((ushort*)C0)[(size_t)(rbase+j)*N + cc] = f2b(fmaxf(vv[j],0.0f));
      } else if(EPI==2){
#pragma unroll
        for(int j=0;j<4;++j){
          size_t o = (size_t)(rbase+j)*N + cc;
          ((float*)C0)[o] = vv[j] + res[o];
        }
      } else { // EPI==5 fused QV + proj
        if(cc < 512){
          int h = cc>>6, d = cc&63;
#pragma unroll
          for(int j=0;j<4;++j){
            int r = rbase + j;
            int b = r>>10, n = r&1023;
            ((ushort*)C1)[(((size_t)(b*8+h))*1024 + n)*64 + d] = f2b(vv[j]);
          }
        } else if(cc < 1024){
          int cl = cc - 512; int h = cl>>6, d = cl&63;
          int b = rbase>>10, n = rbase&1023;
          ushort4 pk;
          pk.x = f2b(vv[0]); pk.y = f2b(vv[1]); pk.z = f2b(vv[2]); pk.w = f2b(vv[3]);
          *(ushort4*)&((ushort*)C2)[(((size_t)(b*8+h))*64 + d)*1024 + n] = pk;
        } else if(cc < 1072){
#pragma unroll
          for(int j=0;j<4;++j)
            ((float*)C0)[(size_t)(rbase+j)*64 + (cc-1024)] = vv[j];
        }
      }
    }
  }
}

// binarize proj -> buckets; ||q||^2 from bf16 Qh -> qn2
__global__ __launch_bounds__(256) void encode_kernel(
    const ushort* __restrict__ Qh, const float* __restrict__ Pr,
    int* __restrict__ buckets, float* __restrict__ qn2){
  int t = blockIdx.x*256 + threadIdx.x;   // 4096*8
  int h = t & 7, row = t >> 3;            // row = b*1024+n
  int b = row >> 10, n = row & 1023;
  int bhn = (b*8+h)*1024 + n;
  const short8* qp = (const short8*)&Qh[(size_t)bhn*DH_];
  float s2 = 0.f;
#pragma unroll
  for(int c=0;c<8;++c){
    short8 v = qp[c];
#pragma unroll
    for(int j=0;j<8;++j){
      float f = b2f((ushort)v[j]);
      s2 += f*f;
    }
  }
  qn2[bhn] = s2;
  const float* pr = Pr + (size_t)row*64 + h*NHYP_;
  int bk = 0;
#pragma unroll
  for(int y=0;y<NHYP_;++y) bk |= (pr[y] >= 0.0f) ? (1<<y) : 0;
  buckets[bhn] = bk;
}

// flash attention, MFMA bf16, fixed-bound softmax (no per-tile reductions).
// 4 waves, 64 q-rows/block. bid = qt*32 + bh -> head-contiguous XCD placement.
__global__ __launch_bounds__(256) void attn_mfma_kernel(
    const ushort* __restrict__ Qh,   // [BH][SEQ][64]
    const ushort* __restrict__ Vt,   // [BH][64][SEQ]
    const int* __restrict__ buckets, // [BH][SEQ]
    const float* __restrict__ qn2,   // [BH][SEQ]  ||q||^2 (bf16-exact)
    float* __restrict__ outp)        // [B][SEQ][E]
{
  int bid = blockIdx.x;
  int bh = bid & 31;
  int qt = bid >> 5;
  int b = bh >> 3, h = bh & 7;
  int tid = threadIdx.x;
  int w = tid >> 6, lane = tid & 63;
  int g = lane >> 4, li = lane & 15;

  __shared__ ushort Ks[2][64*64];   // swizzled rows of 128B
  __shared__ ushort Vs[2][64*64];   // Vs[d][key], swizzled
  __shared__ ushort Ps[64*68];      // padded, linear
  __shared__ int bks[2][64];
  __shared__ int bqs[64];
  __shared__ float mred[4];

  const ushort* Qbase = Qh + (size_t)bh*SEQ_*DH_;
  const ushort* Vbase = Vt + (size_t)bh*DH_*SEQ_;
  const int* Bb = buckets + bh*SEQ_;
  const float* qn = qn2 + bh*SEQ_;
  int q0 = qt*64;

  auto issue = [&](int kt, int pb){
    int j0 = kt*64;
#pragma unroll
    for(int it=0; it<2; ++it){
      int c = it*256 + tid; int r = c>>3; int ks = ((c&7)^(r&7))*8;
      gload16(&Qbase[(size_t)(j0+r)*DH_ + ks], &Ks[pb][it*2048 + w*512]);
      gload16(&Vbase[(size_t)r*SEQ_ + j0 + ks], &Vs[pb][it*2048 + w*512]);
    }
    if(tid < 16) gload16(&Bb[j0 + tid*4], &bks[pb][0]);
  };

  issue(0, 0);
  // Q fragments straight from global (coalesced, linear)
  short8 qa[2];
  int qrow = q0 + w*16 + li;
#pragma unroll
  for(int kc=0; kc<2; ++kc)
    qa[kc] = *(const short8*)&Qbase[(size_t)qrow*DH_ + kc*32 + g*8];
  if(tid < 64) bqs[tid] = Bb[q0 + tid];

  // head-wide max ||q|| (keys == queries for self-attention)
  float mx = 0.f;
  for(int i=tid;i<SEQ_;i+=256) mx = fmaxf(mx, qn[i]);
#pragma unroll
  for(int o=32;o;o>>=1) mx = fmaxf(mx, __shfl_xor(mx, o, 64));
  if(lane==0) mred[w] = mx;
  __syncthreads();
  float maxn = sqrtf(fmaxf(fmaxf(mred[0],mred[1]), fmaxf(mred[2],mred[3])));

  const float invsq = 0.04419417382415922f;  // 1/sqrt(512)
  const float c63 = invsq * 63.0f;
  // per-row upper bound on logits (Cauchy-Schwarz) + bf16 slack
  float Mrow[4];
#pragma unroll
  for(int i=0;i<4;++i)
    Mrow[i] = c63 * sqrtf(qn[q0 + w*16 + g*4 + i]) * maxn + 1.0f;

  f32x4 acc_o[4] = {};
  float psum[4] = {0.f,0.f,0.f,0.f};

  for(int kt=0; kt<16; ++kt){
    if(kt < 15) issue(kt+1, (kt+1)&1);
    int pb = kt&1;

    // S = Q K^T (swizzled frag reads)
    f32x4 accs[4];
    __builtin_amdgcn_s_setprio(1);
#pragma unroll
    for(int nt=0; nt<4; ++nt){
      f32x4 z = {};
#pragma unroll
      for(int kc=0; kc<2; ++kc){
        short8 kb = *(const short8*)&Ks[pb][(nt*16+li)*64 + (((kc*4+g)^(li&7))*8)];
        z = __builtin_amdgcn_mfma_f32_16x16x32_bf16(qa[kc], kb, z, 0,0,0);
      }
      accs[nt] = z;
    }
    __builtin_amdgcn_s_setprio(0);
    int bkc[4];
#pragma unroll
    for(int nt=0;nt<4;++nt) bkc[nt] = bks[pb][nt*16 + li];

    // p = exp(logit - M_row); no max-tracking, no rescale
#pragma unroll
    for(int i=0;i<4;++i){
      int rloc = w*16 + g*4 + i;
      int bq = bqs[rloc];
      float rs = 0.f;
#pragma unroll
      for(int nt=0;nt<4;++nt){
        float cnt = (bkc[nt] == bq) ? 63.f : 62.f;
        float e = __expf(accs[nt][i] * (invsq * cnt) - Mrow[i]);
        rs += e;
        Ps[rloc*68 + nt*16 + li] = f2b(e);
      }
      psum[i] += rs;
    }
    // O += P @ V
    __builtin_amdgcn_s_setprio(1);
#pragma unroll
    for(int dt=0; dt<4; ++dt){
      f32x4 z = acc_o[dt];
#pragma unroll
      for(int kc=0; kc<2; ++kc){
        short8 pa = *(const short8*)&Ps[(w*16+li)*68 + kc*32 + g*8];
        short8 vb = *(const short8*)&Vs[pb][(dt*16+li)*64 + (((kc*4+g)^(li&7))*8)];
        z = __builtin_amdgcn_mfma_f32_16x16x32_bf16(pa, vb, z, 0,0,0);
      }
      acc_o[dt] = z;
    }
    __builtin_amdgcn_s_setprio(0);
    __syncthreads();
  }
  // one-time row-sum reduction across the 16 li lanes of each group
#pragma unroll
  for(int i=0;i<4;++i){
#pragma unroll
    for(int o=8;o;o>>=1) psum[i] += __shfl_xor(psum[i], o, 64);
  }
  float* obase = outp + ((size_t)(b*SEQ_ + q0 + w*16 + g*4))*E_ + h*DH_;
#pragma unroll
  for(int i=0;i<4;++i){
    float inv = 1.0f / fmaxf(psum[i], 1e-35f);
#pragma unroll
    for(int dt=0;dt<4;++dt)
      obase[(size_t)i*E_ + dt*16 + li] = acc_o[dt][i] * inv;
  }
}

// layernorm over E=512: one wave per row, float4 vectorized, no barriers
__global__ __launch_bounds__(256) void ln_kernel(
    const float* __restrict__ in, const float* __restrict__ g,
    const float* __restrict__ bb, float* __restrict__ outp,
    ushort* __restrict__ oh){
  int row = blockIdx.x*4 + (threadIdx.x>>6);
  int lane = threadIdx.x & 63;
  const float4* xr = (const float4*)(in + (size_t)row*E_);
  float4 v0 = xr[lane*2], v1 = xr[lane*2+1];
  float s  = v0.x+v0.y+v0.z+v0.w + v1.x+v1.y+v1.z+v1.w;
  float s2 = v0.x*v0.x+v0.y*v0.y+v0.z*v0.z+v0.w*v0.w
           + v1.x*v1.x+v1.y*v1.y+v1.z*v1.z+v1.w*v1.w;
#pragma unroll
  for(int o=32;o;o>>=1){ s += __shfl_xor(s,o,64); s2 += __shfl_xor(s2,o,64); }
  float mean = s*(1.0f/E_);
  float var  = s2*(1.0f/E_) - mean*mean;
  float inv = rsqrtf(var + 1e-5f);
  const float4* g4 = (const float4*)(g) + lane*2;
  const float4* b4 = (const float4*)(bb) + lane*2;
  float4 g0 = g4[0], g1 = g4[1], b0 = b4[0], b1 = b4[1];
  float4 y0, y1;
  y0.x=(v0.x-mean)*inv*g0.x+b0.x; y0.y=(v0.y-mean)*inv*g0.y+b0.y;
  y0.z=(v0.z-mean)*inv*g0.z+b0.z; y0.w=(v0.w-mean)*inv*g0.w+b0.w;
  y1.x=(v1.x-mean)*inv*g1.x+b1.x; y1.y=(v1.y-mean)*inv*g1.y+b1.y;
  y1.z=(v1.z-mean)*inv*g1.z+b1.z; y1.w=(v1.w-mean)*inv*g1.w+b1.w;
  float4* orow = (float4*)(outp + (size_t)row*E_) + lane*2;
  orow[0] = y0; orow[1] = y1;
  ushort hs[8];
  hs[0]=f2b(y0.x); hs[1]=f2b(y0.y); hs[2]=f2b(y0.z); hs[3]=f2b(y0.w);
  hs[4]=f2b(y1.x); hs[5]=f2b(y1.y); hs[6]=f2b(y1.z); hs[7]=f2b(y1.w);
  *(uint4*)&oh[(size_t)row*E_ + lane*8] = *(uint4*)hs;
}

__global__ void final_partial(const float* __restrict__ x, const float* __restrict__ Wm,
                              float* __restrict__ part){
  int b  = blockIdx.x >> 7;
  int ch = blockIdx.x & 127;
  const float* xb = x + (size_t)b*SEQ_*E_;
  int k0 = ch*4096;
  float acc[NC_] = {};
  for(int k=k0+threadIdx.x; k<k0+4096; k+=256){
    float xv = xb[k];
    const float* wrow = Wm + (size_t)k*NC_;
#pragma unroll
    for(int c=0;c<NC_;++c) acc[c] += xv*wrow[c];
  }
#pragma unroll
  for(int c=0;c<NC_;++c) acc[c] = wave_rsum(acc[c]);
  __shared__ float r[4][NC_];
  int w = threadIdx.x>>6, lane = threadIdx.x&63;
  if(lane==0){
#pragma unroll
    for(int c=0;c<NC_;++c) r[w][c] = acc[c];
  }
  __syncthreads();
  if(threadIdx.x==0){
#pragma unroll
    for(int c=0;c<NC_;++c)
      part[(size_t)blockIdx.x*NC_ + c] = r[0][c]+r[1][c]+r[2][c]+r[3][c];
  }
}

__global__ void final_reduce(const float* __restrict__ part, const float* __restrict__ bm,
                             float* __restrict__ out){
  int t = threadIdx.x;
  if(t >= B_*NC_) return;
  int b = t / NC_, c = t % NC_;
  float s = bm[c];
  for(int i=0;i<128;++i) s += part[(size_t)(b*128+i)*NC_ + c];
  out[t] = s;
}

extern "C" void kernel_launch(void* const* d_in, const int* in_sizes, int n_in,
                              void* d_out, int out_size, void* d_ws, size_t ws_size,
                              hipStream_t stream){
  const int*   inp   = (const int*)d_in[0];
  const float* emb   = (const float*)d_in[1];
  const float* gamma = (const float*)d_in[2];
  const float* beta  = (const float*)d_in[3];
  const float* Wq    = (const float*)d_in[4];
  const float* bq    = (const float*)d_in[5];
  const float* Wv    = (const float*)d_in[6];
  const float* bv    = (const float*)d_in[7];
  const float* hyper = (const float*)d_in[8];
  const float* W1    = (const float*)d_in[9];
  const float* b1    = (const float*)d_in[10];
  const float* W2    = (const float*)d_in[11];
  const float* b2    = (const float*)d_in[12];
  const float* Wm    = (const float*)d_in[13];
  const float* bm    = (const float*)d_in[14];
  float* out = (float*)d_out;

  char* ws = (char*)d_ws;
  size_t off = 0;
  auto alloc = [&](size_t bytes)->void*{
    void* p = ws + off; off += (bytes + 255) & ~(size_t)255; return p;
  };
  const size_t NTOK = (size_t)B_*SEQ_;
  float*  X    = (float*)alloc(NTOK*E_*sizeof(float));
  float*  A    = (float*)alloc(NTOK*E_*sizeof(float));
  float*  Pr   = (float*)alloc(NTOK*64*sizeof(float));     // proj, stride 64
  ushort* Xh   = (ushort*)alloc(NTOK*E_*sizeof(ushort));
  ushort* Hh   = (ushort*)alloc(NTOK*HID_*sizeof(ushort));
  int*    Bk   = (int*)  alloc((size_t)BH_*SEQ_*sizeof(int));
  float*  Qn2  = (float*)alloc((size_t)BH_*SEQ_*sizeof(float));
  float*  Pp   = (float*)alloc((size_t)B_*128*NC_*sizeof(float));
  ushort* Qh   = (ushort*)alloc((size_t)BH_*SEQ_*DH_*sizeof(ushort));
  ushort* Vt   = (ushort*)alloc((size_t)BH_*DH_*SEQ_*sizeof(ushort));
  ushort* WcatT= (ushort*)alloc((size_t)NCAT_*E_*sizeof(ushort));
  ushort* W1T  = (ushort*)alloc((size_t)HID_*E_*sizeof(ushort));
  ushort* W2T  = (ushort*)alloc((size_t)E_*HID_*sizeof(ushort));
  float*  bcat = (float*)alloc(NCAT_*sizeof(float));
  (void)ws_size; (void)in_sizes; (void)n_in; (void)out_size;

  // one-time weight prep
  transpose_cast<<<dim3(E_/32,  E_/32),  256, 0, stream>>>(Wq, WcatT, E_, E_);
  transpose_cast<<<dim3(E_/32,  E_/32),  256, 0, stream>>>(Wv, WcatT + (size_t)512*E_, E_, E_);
  wproj_build<<<128, 256, 0, stream>>>(Wq, hyper, WcatT);
  transpose_cast<<<dim3(HID_/32,E_/32),  256, 0, stream>>>(W1, W1T, E_, HID_);
  transpose_cast<<<dim3(E_/32,  HID_/32),256, 0, stream>>>(W2, W2T, HID_, E_);
  bias_build<<<5, 256, 0, stream>>>(bq, bv, hyper, bcat);

  embed_pe_kernel<<<B_*SEQ_, 256, 0, stream>>>(inp, emb, X, Xh);

  dim3 gQV(NCAT_/64, (B_*SEQ_)/128);   // 17 x 32 = 544 blocks
  dim3 gF1(HID_/128, (B_*SEQ_)/128);   // 16 x 32 = 512 blocks
  dim3 gF2(E_/64,    (B_*SEQ_)/128);   //  8 x 32 = 256 blocks
  for(int l=0;l<ENC_;++l){
    gemm_mfma<128,64,5><<<gQV, 256, 0, stream>>>(Xh, WcatT, bcat, nullptr, Pr, Qh, Vt, B_*SEQ_, NCAT_, E_);
    encode_kernel<<<(B_*SEQ_*H_)/256, 256, 0, stream>>>(Qh, Pr, Bk, Qn2);
    attn_mfma_kernel<<<BH_*16, 256, 0, stream>>>(Qh, Vt, Bk, Qn2, A);
    ln_kernel<<<B_*SEQ_/4, 256, 0, stream>>>(A, gamma, beta, X, Xh);
    gemm_mfma<128,128,1><<<gF1, 256, 0, stream>>>(Xh, W1T, b1, nullptr, Hh, nullptr, nullptr, B_*SEQ_, HID_, E_);
    gemm_mfma<128,64,2><<<gF2, 256, 0, stream>>>(Hh, W2T, b2, X, A, nullptr, nullptr, B_*SEQ_, E_, HID_);
    ln_kernel<<<B_*SEQ_/4, 256, 0, stream>>>(A, gamma, beta, X, Xh);
  }
  final_partial<<<B_*128, 256, 0, stream>>>(X, Wm, Pp);
  final_reduce<<<1, 32, 0, stream>>>(Pp, bm, out);
}

// Round 9
// 642.385 us; speedup vs baseline: 1.0126x; 1.0126x over previous
//
#include <hip/hip_runtime.h>
#include <hip/hip_bf16.h>
#include <math.h>

#define B_    4
#define SEQ_  1024
#define E_    512
#define H_    8
#define DH_   64
#define NHYP_ 6
#define HID_  2048
#define NC_   6
#define ENC_  6
#define BH_   (B_*H_)
#define NTOK_ 4096
#define NCAT_ 1088   // 512 Q + 512 V + 48 proj + 16 pad

typedef __attribute__((ext_vector_type(8))) short short8;
typedef __attribute__((ext_vector_type(4))) float f32x4;

static __device__ __forceinline__ float wave_rsum(float v){
#pragma unroll
  for(int o=32;o;o>>=1) v += __shfl_down(v,o,64);
  return v;
}
static __device__ __forceinline__ ushort f2b(float v){
  __hip_bfloat16 h = __float2bfloat16(v);
  return *(ushort*)&h;
}
static __device__ __forceinline__ float b2f(ushort u){
  unsigned int x = ((unsigned int)u) << 16;
  return *(float*)&x;
}
// async global->LDS, 16B/lane; LDS dest = wave-uniform base + lane*16 (linear)
static __device__ __forceinline__ void gload16(const void* g, void* l){
  __builtin_amdgcn_global_load_lds(
      (const __attribute__((address_space(1))) void*)g,
      (__attribute__((address_space(3))) void*)l,
      16, 0, 0);
}

// x[b,s,:] = emb[idx[b,s],:] + pos_encoding(s,:)   (fp32 + bf16 copies)
__global__ void embed_pe_kernel(const int* __restrict__ inp, const float* __restrict__ emb,
                                float* __restrict__ x, ushort* __restrict__ xh){
  int row = blockIdx.x;            // b*SEQ + s
  int s = row & (SEQ_-1);
  int idx = inp[row];
  const float* er = emb + (size_t)idx*E_;
  float* xr = x + (size_t)row*E_;
  ushort* hr = xh + (size_t)row*E_;
  for(int c=threadIdx.x;c<E_;c+=blockDim.x){
    int i = c>>1;
    float div = expf(-(float)i * 0.0359778920780319646f);
    float ang = (float)s * div;
    float pe = (c&1) ? cosf(ang) : sinf(ang);
    float v = er[c] + pe;
    xr[c] = v;
    hr[c] = f2b(v);
  }
}

// one-time: W[K][N] fp32 -> Wt[N][K] bf16
__global__ __launch_bounds__(256) void transpose_cast(
    const float* __restrict__ W, ushort* __restrict__ Wt, int K, int N){
  __shared__ float T[32][33];
  int tx = threadIdx.x & 31, ty = threadIdx.x >> 5;   // 32x8
  int n0 = blockIdx.x*32, k0 = blockIdx.y*32;
#pragma unroll
  for(int i=0;i<32;i+=8) T[ty+i][tx] = W[(size_t)(k0+ty+i)*N + n0+tx];
  __syncthreads();
#pragma unroll
  for(int i=0;i<32;i+=8)
    Wt[(size_t)(n0+ty+i)*K + k0+tx] = f2b(T[tx][ty+i]);
}

// one-time: W_projT rows of WcatT. WcatT[1024+c][k] = sum_d Wq[k][h*64+d]*hyper[d*6+y]
__global__ void wproj_build(const float* __restrict__ Wq, const float* __restrict__ hyper,
                            ushort* __restrict__ WcatT){
  int t = blockIdx.x*256 + threadIdx.x;   // 64*512
  int c = t >> 9, k = t & 511;
  float s = 0.f;
  if(c < 48){
    int h = c/6, y = c%6;
    const float* wr = Wq + (size_t)k*E_ + h*DH_;
    for(int d=0;d<DH_;++d) s += wr[d]*hyper[d*NHYP_+y];
  }
  WcatT[(size_t)(1024+c)*E_ + k] = f2b(s);
}

// one-time: concatenated bias [bq | bv | bproj | 0]
__global__ void bias_build(const float* __restrict__ bq, const float* __restrict__ bv,
                           const float* __restrict__ hyper, float* __restrict__ bcat){
  int t = blockIdx.x*256 + threadIdx.x;
  if(t >= NCAT_) return;
  float v;
  if(t < 512) v = bq[t];
  else if(t < 1024) v = bv[t-512];
  else if(t < 1072){
    int c = t - 1024, h = c/6, y = c%6;
    float s = hyper[DH_*NHYP_ + y];
    for(int d=0;d<DH_;++d) s += bq[h*DH_+d]*hyper[d*NHYP_+y];
    v = s;
  } else v = 0.f;
  bcat[t] = v;
}

// C = A[M,K](bf16) @ Bt[N,K]^T(bf16) + bias.
// BK=64, swizzled LDS (XOR chunk^(row&7)), double-buffered, 1 barrier/K-step.
// EPI 0: fp32->C0. 1: relu->bf16 C0. 2: +res -> fp32 C0.
// 5: fused QVproj: cc<512 -> Qh=C1 (bf16 head layout); cc<1024 -> Vt=C2 (bf16
//    transposed); cc<1072 -> proj fp32 -> C0 (stride 64); else discard.
template<int BM, int BN, int EPI>
__global__ __launch_bounds__(256) void gemm_mfma(
    const ushort* __restrict__ A, const ushort* __restrict__ Bt,
    const float* __restrict__ bias, const float* __restrict__ res,
    void* __restrict__ C0, void* __restrict__ C1, void* __restrict__ C2,
    int M, int N, int K)
{
  constexpr int MI = BM/32, NI = BN/32;
  constexpr int ACH = BM/32, BCH = BN/32;   // gload iters (BM*8 chunks / 256 thr)
  __shared__ ushort As[2][BM*64];
  __shared__ ushort Bs[2][BN*64];
  int tid = threadIdx.x;
  int w = tid>>6, lane = tid&63, g = lane>>4, li = lane&15;
  int wr = w>>1, wc = w&1;
  int bm = blockIdx.y*BM, bn = blockIdx.x*BN;
  int NK = K>>6;

  f32x4 acc[MI][NI] = {};

  auto issue = [&](int ks, int pb){
    int k0 = ks*64;
#pragma unroll
    for(int it=0; it<ACH; ++it){
      int c = it*256 + tid; int r = c>>3; int kq = ((c&7)^(r&7))*8;
      gload16(&A[(size_t)(bm+r)*K + k0 + kq], &As[pb][it*2048 + w*512]);
    }
#pragma unroll
    for(int it=0; it<BCH; ++it){
      int c = it*256 + tid; int r = c>>3; int kq = ((c&7)^(r&7))*8;
      gload16(&Bt[(size_t)(bn+r)*K + k0 + kq], &Bs[pb][it*2048 + w*512]);
    }
  };

  issue(0, 0);
  __syncthreads();
  for(int ks=0; ks<NK; ++ks){
    if(ks+1 < NK) issue(ks+1, (ks+1)&1);
    int pb = ks&1;
#pragma unroll
    for(int kc=0; kc<2; ++kc){
      short8 af[MI], bf[NI];
#pragma unroll
      for(int mi=0;mi<MI;++mi)
        af[mi] = *(const short8*)&As[pb][(wr*(BM/2)+mi*16+li)*64 + (((kc*4+g)^(li&7))*8)];
#pragma unroll
      for(int ni=0;ni<NI;++ni)
        bf[ni] = *(const short8*)&Bs[pb][(wc*(BN/2)+ni*16+li)*64 + (((kc*4+g)^(li&7))*8)];
#pragma unroll
      for(int mi=0;mi<MI;++mi)
#pragma unroll
        for(int ni=0;ni<NI;++ni)
          acc[mi][ni] = __builtin_amdgcn_mfma_f32_16x16x32_bf16(af[mi], bf[ni], acc[mi][ni], 0,0,0);
    }
    __syncthreads();
  }

#pragma unroll
  for(int mi=0;mi<MI;++mi){
    int rbase = bm + wr*(BM/2) + mi*16 + g*4;
#pragma unroll
    for(int ni=0;ni<NI;++ni){
      int cc = bn + wc*(BN/2) + ni*16 + li;
      float bv = bias[cc];
      float vv[4];
#pragma unroll
      for(int j=0;j<4;++j) vv[j] = acc[mi][ni][j] + bv;
      if(EPI==0){
#pragma unroll
        for(int j=0;j<4;++j) ((float*)C0)[(size_t)(rbase+j)*N + cc] = vv[j];
      } else if(EPI==1){
#pragma unroll
        for(int j=0;j<4;++j) ((ushort*)C0)[(size_t)(rbase+j)*N + cc] = f2b(fmaxf(vv[j],0.0f));
      } else if(EPI==2){
#pragma unroll
        for(int j=0;j<4;++j){
          size_t o = (size_t)(rbase+j)*N + cc;
          ((float*)C0)[o] = vv[j] + res[o];
        }
      } else { // EPI==5 fused QV + proj
        if(cc < 512){
          int h = cc>>6, d = cc&63;
#pragma unroll
          for(int j=0;j<4;++j){
            int r = rbase + j;
            int b = r>>10, n = r&1023;
            ((ushort*)C1)[(((size_t)(b*8+h))*1024 + n)*64 + d] = f2b(vv[j]);
          }
        } else if(cc < 1024){
          int cl = cc - 512; int h = cl>>6, d = cl&63;
          int b = rbase>>10, n = rbase&1023;
          ushort4 pk;
          pk.x = f2b(vv[0]); pk.y = f2b(vv[1]); pk.z = f2b(vv[2]); pk.w = f2b(vv[3]);
          *(ushort4*)&((ushort*)C2)[(((size_t)(b*8+h))*64 + d)*1024 + n] = pk;
        } else if(cc < 1072){
#pragma unroll
          for(int j=0;j<4;++j)
            ((float*)C0)[(size_t)(rbase+j)*64 + (cc-1024)] = vv[j];
        }
      }
    }
  }
}

// binarize proj -> buckets; ||q||^2 from bf16 Qh -> qn2
__global__ __launch_bounds__(256) void encode_kernel(
    const ushort* __restrict__ Qh, const float* __restrict__ Pr,
    int* __restrict__ buckets, float* __restrict__ qn2){
  int t = blockIdx.x*256 + threadIdx.x;   // 4096*8
  int h = t & 7, row = t >> 3;            // row = b*1024+n
  int b = row >> 10, n = row & 1023;
  int bhn = (b*8+h)*1024 + n;
  const short8* qp = (const short8*)&Qh[(size_t)bhn*DH_];
  float s2 = 0.f;
#pragma unroll
  for(int c=0;c<8;++c){
    short8 v = qp[c];
#pragma unroll
    for(int j=0;j<8;++j){
      float f = b2f((ushort)v[j]);
      s2 += f*f;
    }
  }
  qn2[bhn] = s2;
  const float* pr = Pr + (size_t)row*64 + h*NHYP_;
  int bk = 0;
#pragma unroll
  for(int y=0;y<NHYP_;++y) bk |= (pr[y] >= 0.0f) ? (1<<y) : 0;
  buckets[bhn] = bk;
}

// flash attention, MFMA bf16, fixed-bound softmax, 2-way K-split.
// bid = (qt*2+half)*32 + bh -> all blocks of head bh land on XCD bh%8.
// Writes UNDIVIDED fp32 partial O and per-row psum; combine_ln finishes.
__global__ __launch_bounds__(256) void attn_mfma_kernel(
    const ushort* __restrict__ Qh,   // [BH][SEQ][64]
    const ushort* __restrict__ Vt,   // [BH][64][SEQ]
    const int* __restrict__ buckets, // [BH][SEQ]
    const float* __restrict__ qn2,   // [BH][SEQ]  ||q||^2 (bf16-exact)
    float* __restrict__ Op,          // [2][NTOK][E] partial O (undivided)
    float* __restrict__ Sp)          // [2][BH][SEQ] partial psum
{
  int bid = blockIdx.x;
  int bh   = bid & 31;
  int half = (bid >> 5) & 1;
  int qt   = bid >> 6;
  int b = bh >> 3, h = bh & 7;
  int tid = threadIdx.x;
  int w = tid >> 6, lane = tid & 63;
  int g = lane >> 4, li = lane & 15;

  __shared__ ushort Ks[2][64*64];   // swizzled rows of 128B
  __shared__ ushort Vs[2][64*64];   // Vs[d][key], swizzled
  __shared__ ushort Ps[64*68];      // padded, linear
  __shared__ int bks[2][64];
  __shared__ int bqs[64];
  __shared__ float mred[4];

  const ushort* Qbase = Qh + (size_t)bh*SEQ_*DH_;
  const ushort* Vbase = Vt + (size_t)bh*DH_*SEQ_;
  const int* Bb = buckets + bh*SEQ_;
  const float* qn = qn2 + bh*SEQ_;
  int q0 = qt*64;
  int kt0 = half*8;

  auto issue = [&](int kt, int pb){
    int j0 = kt*64;
#pragma unroll
    for(int it=0; it<2; ++it){
      int c = it*256 + tid; int r = c>>3; int ks = ((c&7)^(r&7))*8;
      gload16(&Qbase[(size_t)(j0+r)*DH_ + ks], &Ks[pb][it*2048 + w*512]);
      gload16(&Vbase[(size_t)r*SEQ_ + j0 + ks], &Vs[pb][it*2048 + w*512]);
    }
    if(tid < 16) gload16(&Bb[j0 + tid*4], &bks[pb][0]);
  };

  issue(kt0, 0);
  // Q fragments straight from global (coalesced, linear)
  short8 qa[2];
  int qrow = q0 + w*16 + li;
#pragma unroll
  for(int kc=0; kc<2; ++kc)
    qa[kc] = *(const short8*)&Qbase[(size_t)qrow*DH_ + kc*32 + g*8];
  if(tid < 64) bqs[tid] = Bb[q0 + tid];

  // head-wide max ||q|| (keys == queries) -- same for both halves
  float mx = 0.f;
  for(int i=tid;i<SEQ_;i+=256) mx = fmaxf(mx, qn[i]);
#pragma unroll
  for(int o=32;o;o>>=1) mx = fmaxf(mx, __shfl_xor(mx, o, 64));
  if(lane==0) mred[w] = mx;
  __syncthreads();
  float maxn = sqrtf(fmaxf(fmaxf(mred[0],mred[1]), fmaxf(mred[2],mred[3])));

  const float invsq = 0.04419417382415922f;  // 1/sqrt(512)
  const float c63 = invsq * 63.0f;
  float Mrow[4];
#pragma unroll
  for(int i=0;i<4;++i)
    Mrow[i] = c63 * sqrtf(qn[q0 + w*16 + g*4 + i]) * maxn + 1.0f;

  f32x4 acc_o[4] = {};
  float psum[4] = {0.f,0.f,0.f,0.f};

  for(int t=0; t<8; ++t){
    int kt = kt0 + t;
    if(t < 7) issue(kt+1, (t+1)&1);
    int pb = t&1;

    // S = Q K^T (swizzled frag reads)
    f32x4 accs[4];
    __builtin_amdgcn_s_setprio(1);
#pragma unroll
    for(int nt=0; nt<4; ++nt){
      f32x4 z = {};
#pragma unroll
      for(int kc=0; kc<2; ++kc){
        short8 kb = *(const short8*)&Ks[pb][(nt*16+li)*64 + (((kc*4+g)^(li&7))*8)];
        z = __builtin_amdgcn_mfma_f32_16x16x32_bf16(qa[kc], kb, z, 0,0,0);
      }
      accs[nt] = z;
    }
    __builtin_amdgcn_s_setprio(0);
    int bkc[4];
#pragma unroll
    for(int nt=0;nt<4;++nt) bkc[nt] = bks[pb][nt*16 + li];

    // p = exp(logit - M_row); no max-tracking, no rescale
#pragma unroll
    for(int i=0;i<4;++i){
      int rloc = w*16 + g*4 + i;
      int bq = bqs[rloc];
      float rs = 0.f;
#pragma unroll
      for(int nt=0;nt<4;++nt){
        float cnt = (bkc[nt] == bq) ? 63.f : 62.f;
        float e = __expf(accs[nt][i] * (invsq * cnt) - Mrow[i]);
        rs += e;
        Ps[rloc*68 + nt*16 + li] = f2b(e);
      }
      psum[i] += rs;
    }
    // O += P @ V
    __builtin_amdgcn_s_setprio(1);
#pragma unroll
    for(int dt=0; dt<4; ++dt){
      f32x4 z = acc_o[dt];
#pragma unroll
      for(int kc=0; kc<2; ++kc){
        short8 pa = *(const short8*)&Ps[(w*16+li)*68 + kc*32 + g*8];
        short8 vb = *(const short8*)&Vs[pb][(dt*16+li)*64 + (((kc*4+g)^(li&7))*8)];
        z = __builtin_amdgcn_mfma_f32_16x16x32_bf16(pa, vb, z, 0,0,0);
      }
      acc_o[dt] = z;
    }
    __builtin_amdgcn_s_setprio(0);
    __syncthreads();
  }
  // row-sum reduction across the 16 li lanes of each group
#pragma unroll
  for(int i=0;i<4;++i){
#pragma unroll
    for(int o=8;o;o>>=1) psum[i] += __shfl_xor(psum[i], o, 64);
  }
  float* obase = Op + (size_t)half*NTOK_*E_
               + ((size_t)(b*SEQ_ + q0 + w*16 + g*4))*E_ + h*DH_;
#pragma unroll
  for(int i=0;i<4;++i){
#pragma unroll
    for(int dt=0;dt<4;++dt)
      obase[(size_t)i*E_ + dt*16 + li] = acc_o[dt][i];
  }
  if(li == 0){
    float* sp = Sp + (size_t)half*BH_*SEQ_ + (size_t)bh*SEQ_ + q0 + w*16 + g*4;
#pragma unroll
    for(int i=0;i<4;++i) sp[i] = psum[i];
  }
}

// combine the two K-halves (divide per head) + layernorm, one wave per row
__global__ __launch_bounds__(256) void combine_ln(
    const float* __restrict__ Op, const float* __restrict__ Sp,
    const float* __restrict__ g, const float* __restrict__ bb,
    float* __restrict__ outp, ushort* __restrict__ oh){
  int row = blockIdx.x*4 + (threadIdx.x>>6);   // b*SEQ+n
  int lane = threadIdx.x & 63;
  int b = row >> 10, n = row & 1023;
  int h = lane >> 3;                            // 8 cols/lane, one head/lane
  size_t sidx = (size_t)(b*8+h)*SEQ_ + n;
  float ps = Sp[sidx] + Sp[(size_t)BH_*SEQ_ + sidx];
  float inv0 = 1.0f / fmaxf(ps, 1e-35f);
  const float4* o1 = (const float4*)(Op + (size_t)row*E_) + lane*2;
  const float4* o2 = (const float4*)(Op + (size_t)NTOK_*E_ + (size_t)row*E_) + lane*2;
  float4 v0 = o1[0], v1 = o1[1], u0 = o2[0], u1 = o2[1];
  v0.x=(v0.x+u0.x)*inv0; v0.y=(v0.y+u0.y)*inv0; v0.z=(v0.z+u0.z)*inv0; v0.w=(v0.w+u0.w)*inv0;
  v1.x=(v1.x+u1.x)*inv0; v1.y=(v1.y+u1.y)*inv0; v1.z=(v1.z+u1.z)*inv0; v1.w=(v1.w+u1.w)*inv0;
  float s  = v0.x+v0.y+v0.z+v0.w + v1.x+v1.y+v1.z+v1.w;
  float s2 = v0.x*v0.x+v0.y*v0.y+v0.z*v0.z+v0.w*v0.w
           + v1.x*v1.x+v1.y*v1.y+v1.z*v1.z+v1.w*v1.w;
#pragma unroll
  for(int o=32;o;o>>=1){ s += __shfl_xor(s,o,64); s2 += __shfl_xor(s2,o,64); }
  float mean = s*(1.0f/E_);
  float var  = s2*(1.0f/E_) - mean*mean;
  float inv = rsqrtf(var + 1e-5f);
  const float4* g4 = (const float4*)(g) + lane*2;
  const float4* b4 = (const float4*)(bb) + lane*2;
  float4 g0 = g4[0], g1 = g4[1], b0 = b4[0], b1 = b4[1];
  float4 y0, y1;
  y0.x=(v0.x-mean)*inv*g0.x+b0.x; y0.y=(v0.y-mean)*inv*g0.y+b0.y;
  y0.z=(v0.z-mean)*inv*g0.z+b0.z; y0.w=(v0.w-mean)*inv*g0.w+b0.w;
  y1.x=(v1.x-mean)*inv*g1.x+b1.x; y1.y=(v1.y-mean)*inv*g1.y+b1.y;
  y1.z=(v1.z-mean)*inv*g1.z+b1.z; y1.w=(v1.w-mean)*inv*g1.w+b1.w;
  float4* orow = (float4*)(outp + (size_t)row*E_) + lane*2;
  orow[0] = y0; orow[1] = y1;
  ushort hs[8];
  hs[0]=f2b(y0.x); hs[1]=f2b(y0.y); hs[2]=f2b(y0.z); hs[3]=f2b(y0.w);
  hs[4]=f2b(y1.x); hs[5]=f2b(y1.y); hs[6]=f2b(y1.z); hs[7]=f2b(y1.w);
  *(uint4*)&oh[(size_t)row*E_ + lane*8] = *(uint4*)hs;
}

// layernorm over E=512: one wave per row, float4 vectorized, no barriers
__global__ __launch_bounds__(256) void ln_kernel(
    const float* __restrict__ in, const float* __restrict__ g,
    const float* __restrict__ bb, float* __restrict__ outp,
    ushort* __restrict__ oh){
  int row = blockIdx.x*4 + (threadIdx.x>>6);
  int lane = threadIdx.x & 63;
  const float4* xr = (const float4*)(in + (size_t)row*E_);
  float4 v0 = xr[lane*2], v1 = xr[lane*2+1];
  float s  = v0.x+v0.y+v0.z+v0.w + v1.x+v1.y+v1.z+v1.w;
  float s2 = v0.x*v0.x+v0.y*v0.y+v0.z*v0.z+v0.w*v0.w
           + v1.x*v1.x+v1.y*v1.y+v1.z*v1.z+v1.w*v1.w;
#pragma unroll
  for(int o=32;o;o>>=1){ s += __shfl_xor(s,o,64); s2 += __shfl_xor(s2,o,64); }
  float mean = s*(1.0f/E_);
  float var  = s2*(1.0f/E_) - mean*mean;
  float inv = rsqrtf(var + 1e-5f);
  const float4* g4 = (const float4*)(g) + lane*2;
  const float4* b4 = (const float4*)(bb) + lane*2;
  float4 g0 = g4[0], g1 = g4[1], b0 = b4[0], b1 = b4[1];
  float4 y0, y1;
  y0.x=(v0.x-mean)*inv*g0.x+b0.x; y0.y=(v0.y-mean)*inv*g0.y+b0.y;
  y0.z=(v0.z-mean)*inv*g0.z+b0.z; y0.w=(v0.w-mean)*inv*g0.w+b0.w;
  y1.x=(v1.x-mean)*inv*g1.x+b1.x; y1.y=(v1.y-mean)*inv*g1.y+b1.y;
  y1.z=(v1.z-mean)*inv*g1.z+b1.z; y1.w=(v1.w-mean)*inv*g1.w+b1.w;
  float4* orow = (float4*)(outp + (size_t)row*E_) + lane*2;
  orow[0] = y0; orow[1] = y1;
  ushort hs[8];
  hs[0]=f2b(y0.x); hs[1]=f2b(y0.y); hs[2]=f2b(y0.z); hs[3]=f2b(y0.w);
  hs[4]=f2b(y1.x); hs[5]=f2b(y1.y); hs[6]=f2b(y1.z); hs[7]=f2b(y1.w);
  *(uint4*)&oh[(size_t)row*E_ + lane*8] = *(uint4*)hs;
}

__global__ void final_partial(const float* __restrict__ x, const float* __restrict__ Wm,
                              float* __restrict__ part){
  int b  = blockIdx.x >> 7;
  int ch = blockIdx.x & 127;
  const float* xb = x + (size_t)b*SEQ_*E_;
  int k0 = ch*4096;
  float acc[NC_] = {};
  for(int k=k0+threadIdx.x; k<k0+4096; k+=256){
    float xv = xb[k];
    const float* wrow = Wm + (size_t)k*NC_;
#pragma unroll
    for(int c=0;c<NC_;++c) acc[c] += xv*wrow[c];
  }
#pragma unroll
  for(int c=0;c<NC_;++c) acc[c] = wave_rsum(acc[c]);
  __shared__ float r[4][NC_];
  int w = threadIdx.x>>6, lane = threadIdx.x&63;
  if(lane==0){
#pragma unroll
    for(int c=0;c<NC_;++c) r[w][c] = acc[c];
  }
  __syncthreads();
  if(threadIdx.x==0){
#pragma unroll
    for(int c=0;c<NC_;++c)
      part[(size_t)blockIdx.x*NC_ + c] = r[0][c]+r[1][c]+r[2][c]+r[3][c];
  }
}

__global__ void final_reduce(const float* __restrict__ part, const float* __restrict__ bm,
                             float* __restrict__ out){
  int t = threadIdx.x;
  if(t >= B_*NC_) return;
  int b = t / NC_, c = t % NC_;
  float s = bm[c];
  for(int i=0;i<128;++i) s += part[(size_t)(b*128+i)*NC_ + c];
  out[t] = s;
}

extern "C" void kernel_launch(void* const* d_in, const int* in_sizes, int n_in,
                              void* d_out, int out_size, void* d_ws, size_t ws_size,
                              hipStream_t stream){
  const int*   inp   = (const int*)d_in[0];
  const float* emb   = (const float*)d_in[1];
  const float* gamma = (const float*)d_in[2];
  const float* beta  = (const float*)d_in[3];
  const float* Wq    = (const float*)d_in[4];
  const float* bq    = (const float*)d_in[5];
  const float* Wv    = (const float*)d_in[6];
  const float* bv    = (const float*)d_in[7];
  const float* hyper = (const float*)d_in[8];
  const float* W1    = (const float*)d_in[9];
  const float* b1    = (const float*)d_in[10];
  const float* W2    = (const float*)d_in[11];
  const float* b2    = (const float*)d_in[12];
  const float* Wm    = (const float*)d_in[13];
  const float* bm    = (const float*)d_in[14];
  float* out = (float*)d_out;

  char* ws = (char*)d_ws;
  size_t off = 0;
  auto alloc = [&](size_t bytes)->void*{
    void* p = ws + off; off += (bytes + 255) & ~(size_t)255; return p;
  };
  const size_t NTOK = (size_t)B_*SEQ_;
  float*  X    = (float*)alloc(NTOK*E_*sizeof(float));
  float*  A    = (float*)alloc(NTOK*E_*sizeof(float));
  float*  Pr   = (float*)alloc(NTOK*64*sizeof(float));     // proj, stride 64
  float*  Op   = (float*)alloc((size_t)2*NTOK*E_*sizeof(float));
  float*  Sp   = (float*)alloc((size_t)2*BH_*SEQ_*sizeof(float));
  ushort* Xh   = (ushort*)alloc(NTOK*E_*sizeof(ushort));
  ushort* Hh   = (ushort*)alloc(NTOK*HID_*sizeof(ushort));
  int*    Bk   = (int*)  alloc((size_t)BH_*SEQ_*sizeof(int));
  float*  Qn2  = (float*)alloc((size_t)BH_*SEQ_*sizeof(float));
  float*  Pp   = (float*)alloc((size_t)B_*128*NC_*sizeof(float));
  ushort* Qh   = (ushort*)alloc((size_t)BH_*SEQ_*DH_*sizeof(ushort));
  ushort* Vt   = (ushort*)alloc((size_t)BH_*DH_*SEQ_*sizeof(ushort));
  ushort* WcatT= (ushort*)alloc((size_t)NCAT_*E_*sizeof(ushort));
  ushort* W1T  = (ushort*)alloc((size_t)HID_*E_*sizeof(ushort));
  ushort* W2T  = (ushort*)alloc((size_t)E_*HID_*sizeof(ushort));
  float*  bcat = (float*)alloc(NCAT_*sizeof(float));
  (void)ws_size; (void)in_sizes; (void)n_in; (void)out_size;

  // one-time weight prep
  transpose_cast<<<dim3(E_/32,  E_/32),  256, 0, stream>>>(Wq, WcatT, E_, E_);
  transpose_cast<<<dim3(E_/32,  E_/32),  256, 0, stream>>>(Wv, WcatT + (size_t)512*E_, E_, E_);
  wproj_build<<<128, 256, 0, stream>>>(Wq, hyper, WcatT);
  transpose_cast<<<dim3(HID_/32,E_/32),  256, 0, stream>>>(W1, W1T, E_, HID_);
  transpose_cast<<<dim3(E_/32,  HID_/32),256, 0, stream>>>(W2, W2T, HID_, E_);
  bias_build<<<5, 256, 0, stream>>>(bq, bv, hyper, bcat);

  embed_pe_kernel<<<B_*SEQ_, 256, 0, stream>>>(inp, emb, X, Xh);

  dim3 gQV(NCAT_/64, (B_*SEQ_)/64);    // 17 x 64 = 1088 blocks
  dim3 gF1(HID_/128, (B_*SEQ_)/128);   // 16 x 32 = 512 blocks
  dim3 gF2(E_/64,    (B_*SEQ_)/64);    //  8 x 64 = 512 blocks
  for(int l=0;l<ENC_;++l){
    gemm_mfma<64,64,5><<<gQV, 256, 0, stream>>>(Xh, WcatT, bcat, nullptr, Pr, Qh, Vt, B_*SEQ_, NCAT_, E_);
    encode_kernel<<<(B_*SEQ_*H_)/256, 256, 0, stream>>>(Qh, Pr, Bk, Qn2);
    attn_mfma_kernel<<<BH_*32, 256, 0, stream>>>(Qh, Vt, Bk, Qn2, Op, Sp);
    combine_ln<<<B_*SEQ_/4, 256, 0, stream>>>(Op, Sp, gamma, beta, X, Xh);
    gemm_mfma<128,128,1><<<gF1, 256, 0, stream>>>(Xh, W1T, b1, nullptr, Hh, nullptr, nullptr, B_*SEQ_, HID_, E_);
    gemm_mfma<64,64,2><<<gF2, 256, 0, stream>>>(Hh, W2T, b2, X, A, nullptr, nullptr, B_*SEQ_, E_, HID_);
    ln_kernel<<<B_*SEQ_/4, 256, 0, stream>>>(A, gamma, beta, X, Xh);
  }
  final_partial<<<B_*128, 256, 0, stream>>>(X, Wm, Pp);
  final_reduce<<<1, 32, 0, stream>>>(Pp, bm, out);
}

// Round 10
// 588.432 us; speedup vs baseline: 1.1055x; 1.0917x over previous
//
#include <hip/hip_runtime.h>
#include <hip/hip_bf16.h>
#include <math.h>

#define B_    4
#define SEQ_  1024
#define E_    512
#define H_    8
#define DH_   64
#define NHYP_ 6
#define HID_  2048
#define NC_   6
#define ENC_  6
#define BH_   (B_*H_)
#define NTOK_ 4096
#define NCAT_ 1088   // 512 Q + 512 V + 48 proj + 16 pad

typedef __attribute__((ext_vector_type(8))) short short8;
typedef __attribute__((ext_vector_type(4))) float f32x4;

static __device__ __forceinline__ float wave_rsum(float v){
#pragma unroll
  for(int o=32;o;o>>=1) v += __shfl_down(v,o,64);
  return v;
}
static __device__ __forceinline__ ushort f2b(float v){
  __hip_bfloat16 h = __float2bfloat16(v);
  return *(ushort*)&h;
}
static __device__ __forceinline__ float b2f(ushort u){
  unsigned int x = ((unsigned int)u) << 16;
  return *(float*)&x;
}
// async global->LDS, 16B/lane; LDS dest = wave-uniform base + lane*16 (linear)
static __device__ __forceinline__ void gload16(const void* g, void* l){
  __builtin_amdgcn_global_load_lds(
      (const __attribute__((address_space(1))) void*)g,
      (__attribute__((address_space(3))) void*)l,
      16, 0, 0);
}

// x[b,s,:] = emb[idx[b,s],:] + pos_encoding(s,:)   (fp32 + bf16 copies)
__global__ void embed_pe_kernel(const int* __restrict__ inp, const float* __restrict__ emb,
                                float* __restrict__ x, ushort* __restrict__ xh){
  int row = blockIdx.x;            // b*SEQ + s
  int s = row & (SEQ_-1);
  int idx = inp[row];
  const float* er = emb + (size_t)idx*E_;
  float* xr = x + (size_t)row*E_;
  ushort* hr = xh + (size_t)row*E_;
  for(int c=threadIdx.x;c<E_;c+=blockDim.x){
    int i = c>>1;
    float div = expf(-(float)i * 0.0359778920780319646f);
    float ang = (float)s * div;
    float pe = (c&1) ? cosf(ang) : sinf(ang);
    float v = er[c] + pe;
    xr[c] = v;
    hr[c] = f2b(v);
  }
}

// one-time: W[K][N] fp32 -> Wt[N][K] bf16
__global__ __launch_bounds__(256) void transpose_cast(
    const float* __restrict__ W, ushort* __restrict__ Wt, int K, int N){
  __shared__ float T[32][33];
  int tx = threadIdx.x & 31, ty = threadIdx.x >> 5;   // 32x8
  int n0 = blockIdx.x*32, k0 = blockIdx.y*32;
#pragma unroll
  for(int i=0;i<32;i+=8) T[ty+i][tx] = W[(size_t)(k0+ty+i)*N + n0+tx];
  __syncthreads();
#pragma unroll
  for(int i=0;i<32;i+=8)
    Wt[(size_t)(n0+ty+i)*K + k0+tx] = f2b(T[tx][ty+i]);
}

// one-time: W_projT rows of WcatT. WcatT[1024+c][k] = sum_d Wq[k][h*64+d]*hyper[d*6+y]
__global__ void wproj_build(const float* __restrict__ Wq, const float* __restrict__ hyper,
                            ushort* __restrict__ WcatT){
  int t = blockIdx.x*256 + threadIdx.x;   // 64*512
  int c = t >> 9, k = t & 511;
  float s = 0.f;
  if(c < 48){
    int h = c/6, y = c%6;
    const float* wr = Wq + (size_t)k*E_ + h*DH_;
    for(int d=0;d<DH_;++d) s += wr[d]*hyper[d*NHYP_+y];
  }
  WcatT[(size_t)(1024+c)*E_ + k] = f2b(s);
}

// one-time: concatenated bias [bq | bv | bproj | 0]
__global__ void bias_build(const float* __restrict__ bq, const float* __restrict__ bv,
                           const float* __restrict__ hyper, float* __restrict__ bcat){
  int t = blockIdx.x*256 + threadIdx.x;
  if(t >= NCAT_) return;
  float v;
  if(t < 512) v = bq[t];
  else if(t < 1024) v = bv[t-512];
  else if(t < 1072){
    int c = t - 1024, h = c/6, y = c%6;
    float s = hyper[DH_*NHYP_ + y];
    for(int d=0;d<DH_;++d) s += bq[h*DH_+d]*hyper[d*NHYP_+y];
    v = s;
  } else v = 0.f;
  bcat[t] = v;
}

// C = A[M,K](bf16) @ Bt[N,K]^T(bf16) + bias.
// BK=64, swizzled LDS (XOR chunk^(row&7)), double-buffered, 1 barrier/K-step.
// K-split via blockIdx.z (kcnt = K/gridDim.z).
// EPI 1: relu->bf16 C0.   EPI 6: raw fp32 partial -> C0 + z*M*N (no bias).
// EPI 5: fused QV+proj+encode: bn<8 -> Qh=C1 + qn2=C3; bn<16 -> Vt=C2;
//        bn==16 -> buckets=C0 (binarized proj).
template<int BM, int BN, int EPI>
__global__ __launch_bounds__(256) void gemm_mfma(
    const ushort* __restrict__ A, const ushort* __restrict__ Bt,
    const float* __restrict__ bias, const float* __restrict__ res,
    void* __restrict__ C0, void* __restrict__ C1, void* __restrict__ C2,
    void* __restrict__ C3, int M, int N, int K)
{
  constexpr int MI = BM/32, NI = BN/32;
  constexpr int ACH = BM/32, BCH = BN/32;   // gload iters (BM*8 chunks / 256 thr)
  __shared__ ushort As[2][BM*64];
  __shared__ ushort Bs[2][BN*64];
  __shared__ float epi[64*49];              // epilogue scratch (EPI==5)
  int tid = threadIdx.x;
  int w = tid>>6, lane = tid&63, g = lane>>4, li = lane&15;
  int wr = w>>1, wc = w&1;
  int bm = blockIdx.y*BM, bn = blockIdx.x*BN;
  int kz = blockIdx.z;
  int kcnt = K / (int)gridDim.z;
  int kbase = kz * kcnt;
  int NK = kcnt >> 6;

  f32x4 acc[MI][NI] = {};

  auto issue = [&](int ks, int pb){
    int k0 = kbase + ks*64;
#pragma unroll
    for(int it=0; it<ACH; ++it){
      int c = it*256 + tid; int r = c>>3; int kq = ((c&7)^(r&7))*8;
      gload16(&A[(size_t)(bm+r)*K + k0 + kq], &As[pb][it*2048 + w*512]);
    }
#pragma unroll
    for(int it=0; it<BCH; ++it){
      int c = it*256 + tid; int r = c>>3; int kq = ((c&7)^(r&7))*8;
      gload16(&Bt[(size_t)(bn+r)*K + k0 + kq], &Bs[pb][it*2048 + w*512]);
    }
  };

  issue(0, 0);
  __syncthreads();
  for(int ks=0; ks<NK; ++ks){
    if(ks+1 < NK) issue(ks+1, (ks+1)&1);
    int pb = ks&1;
#pragma unroll
    for(int kc=0; kc<2; ++kc){
      short8 af[MI], bf[NI];
#pragma unroll
      for(int mi=0;mi<MI;++mi)
        af[mi] = *(const short8*)&As[pb][(wr*(BM/2)+mi*16+li)*64 + (((kc*4+g)^(li&7))*8)];
#pragma unroll
      for(int ni=0;ni<NI;++ni)
        bf[ni] = *(const short8*)&Bs[pb][(wc*(BN/2)+ni*16+li)*64 + (((kc*4+g)^(li&7))*8)];
#pragma unroll
      for(int mi=0;mi<MI;++mi)
#pragma unroll
        for(int ni=0;ni<NI;++ni)
          acc[mi][ni] = __builtin_amdgcn_mfma_f32_16x16x32_bf16(af[mi], bf[ni], acc[mi][ni], 0,0,0);
    }
    __syncthreads();
  }

  if(EPI==5){
    if(bn < 512){            // ---- Q path: Qh bf16 + row qn2 ----
      int h = bn >> 6;       // BN=64 -> one head per column block
#pragma unroll
      for(int mi=0;mi<MI;++mi){
        int rbase = bm + wr*(BM/2) + mi*16 + g*4;
        float q2s[4] = {0.f,0.f,0.f,0.f};
#pragma unroll
        for(int ni=0;ni<NI;++ni){
          int cc = bn + wc*(BN/2) + ni*16 + li;
          float bv = bias[cc];
          int d = cc & 63;
#pragma unroll
          for(int j=0;j<4;++j){
            float vvf = acc[mi][ni][j] + bv;
            ushort ub = f2b(vvf);
            int r = rbase + j; int b = r>>10, n = r&1023;
            ((ushort*)C1)[(((size_t)(b*8+h))*1024 + n)*64 + d] = ub;
            float f = b2f(ub);
            q2s[j] += f*f;
          }
        }
#pragma unroll
        for(int j=0;j<4;++j){
#pragma unroll
          for(int o=8;o;o>>=1) q2s[j] += __shfl_xor(q2s[j], o, 64);
        }
        if(li==0){
#pragma unroll
          for(int j=0;j<4;++j)
            epi[(wr*(BM/2)+mi*16+g*4+j)*2 + wc] = q2s[j];
        }
      }
      __syncthreads();
      if(tid < 64){
        int r = bm + tid; int b = r>>10, n = r&1023;
        ((float*)C3)[((size_t)(b*8+h))*1024 + n] = epi[tid*2] + epi[tid*2+1];
      }
    } else if(bn < 1024){    // ---- V path: Vt bf16 transposed ----
#pragma unroll
      for(int mi=0;mi<MI;++mi){
        int rbase = bm + wr*(BM/2) + mi*16 + g*4;
        int b = rbase>>10, n = rbase&1023;
#pragma unroll
        for(int ni=0;ni<NI;++ni){
          int cc = bn + wc*(BN/2) + ni*16 + li;
          float bv = bias[cc];
          int cl = cc - 512; int h = cl>>6, d = cl&63;
          ushort4 pk;
          pk.x = f2b(acc[mi][ni][0]+bv); pk.y = f2b(acc[mi][ni][1]+bv);
          pk.z = f2b(acc[mi][ni][2]+bv); pk.w = f2b(acc[mi][ni][3]+bv);
          *(ushort4*)&((ushort*)C2)[(((size_t)(b*8+h))*64 + d)*1024 + n] = pk;
        }
      }
    } else {                 // ---- proj path: binarize -> buckets ----
#pragma unroll
      for(int mi=0;mi<MI;++mi){
        int rloc = wr*(BM/2) + mi*16 + g*4;
#pragma unroll
        for(int ni=0;ni<NI;++ni){
          int c = wc*(BN/2) + ni*16 + li;   // 0..63; valid < 48
          if(c < 48){
            float bv = bias[1024 + c];
#pragma unroll
            for(int j=0;j<4;++j)
              epi[(rloc+j)*49 + c] = acc[mi][ni][j] + bv;
          }
        }
      }
      __syncthreads();
      if(tid < 64){
        int r = bm + tid; int b = r>>10, n = r&1023;
#pragma unroll
        for(int h=0;h<8;++h){
          int bk = 0;
#pragma unroll
          for(int y=0;y<NHYP_;++y)
            bk |= (epi[tid*49 + h*NHYP_ + y] >= 0.0f) ? (1<<y) : 0;
          ((int*)C0)[((size_t)(b*8+h))*1024 + n] = bk;
        }
      }
    }
    return;
  }

  // generic epilogues
#pragma unroll
  for(int mi=0;mi<MI;++mi){
    int rbase = bm + wr*(BM/2) + mi*16 + g*4;
#pragma unroll
    for(int ni=0;ni<NI;++ni){
      int cc = bn + wc*(BN/2) + ni*16 + li;
      float bv = (EPI==6) ? 0.0f : bias[cc];
      float vv[4];
#pragma unroll
      for(int j=0;j<4;++j) vv[j] = acc[mi][ni][j] + bv;
      if(EPI==1){
#pragma unroll
        for(int j=0;j<4;++j) ((ushort*)C0)[(size_t)(rbase+j)*N + cc] = f2b(fmaxf(vv[j],0.0f));
      } else if(EPI==6){
        float* dst = (float*)C0 + (size_t)kz*M*N;
#pragma unroll
        for(int j=0;j<4;++j) dst[(size_t)(rbase+j)*N + cc] = vv[j];
      } else if(EPI==2){
#pragma unroll
        for(int j=0;j<4;++j){
          size_t o = (size_t)(rbase+j)*N + cc;
          ((float*)C0)[o] = vv[j] + res[o];
        }
      } else {
#pragma unroll
        for(int j=0;j<4;++j) ((float*)C0)[(size_t)(rbase+j)*N + cc] = vv[j];
      }
    }
  }
}

// flash attention, MFMA bf16, fixed-bound softmax (single pass over 16 K-tiles).
// 4 waves, 64 q-rows/block. bid = qt*32 + bh -> head-contiguous XCD placement.
__global__ __launch_bounds__(256) void attn_mfma_kernel(
    const ushort* __restrict__ Qh,   // [BH][SEQ][64]
    const ushort* __restrict__ Vt,   // [BH][64][SEQ]
    const int* __restrict__ buckets, // [BH][SEQ]
    const float* __restrict__ qn2,   // [BH][SEQ]  ||q||^2 (bf16-exact)
    float* __restrict__ outp)        // [B][SEQ][E]
{
  int bid = blockIdx.x;
  int bh = bid & 31;
  int qt = bid >> 5;
  int b = bh >> 3, h = bh & 7;
  int tid = threadIdx.x;
  int w = tid >> 6, lane = tid & 63;
  int g = lane >> 4, li = lane & 15;

  __shared__ ushort Ks[2][64*64];   // swizzled rows of 128B
  __shared__ ushort Vs[2][64*64];   // Vs[d][key], swizzled
  __shared__ ushort Ps[64*68];      // padded, linear
  __shared__ int bks[2][64];
  __shared__ int bqs[64];
  __shared__ float mred[4];

  const ushort* Qbase = Qh + (size_t)bh*SEQ_*DH_;
  const ushort* Vbase = Vt + (size_t)bh*DH_*SEQ_;
  const int* Bb = buckets + bh*SEQ_;
  const float* qn = qn2 + bh*SEQ_;
  int q0 = qt*64;

  auto issue = [&](int kt, int pb){
    int j0 = kt*64;
#pragma unroll
    for(int it=0; it<2; ++it){
      int c = it*256 + tid; int r = c>>3; int ks = ((c&7)^(r&7))*8;
      gload16(&Qbase[(size_t)(j0+r)*DH_ + ks], &Ks[pb][it*2048 + w*512]);
      gload16(&Vbase[(size_t)r*SEQ_ + j0 + ks], &Vs[pb][it*2048 + w*512]);
    }
    if(tid < 16) gload16(&Bb[j0 + tid*4], &bks[pb][0]);
  };

  issue(0, 0);
  // Q fragments straight from global (coalesced, linear)
  short8 qa[2];
  int qrow = q0 + w*16 + li;
#pragma unroll
  for(int kc=0; kc<2; ++kc)
    qa[kc] = *(const short8*)&Qbase[(size_t)qrow*DH_ + kc*32 + g*8];
  if(tid < 64) bqs[tid] = Bb[q0 + tid];

  // head-wide max ||q|| (keys == queries for self-attention)
  float mx = 0.f;
  for(int i=tid;i<SEQ_;i+=256) mx = fmaxf(mx, qn[i]);
#pragma unroll
  for(int o=32;o;o>>=1) mx = fmaxf(mx, __shfl_xor(mx, o, 64));
  if(lane==0) mred[w] = mx;
  __syncthreads();
  float maxn = sqrtf(fmaxf(fmaxf(mred[0],mred[1]), fmaxf(mred[2],mred[3])));

  const float invsq = 0.04419417382415922f;  // 1/sqrt(512)
  const float c63 = invsq * 63.0f;
  // per-row upper bound on logits (Cauchy-Schwarz) + bf16 slack
  float Mrow[4];
#pragma unroll
  for(int i=0;i<4;++i)
    Mrow[i] = c63 * sqrtf(qn[q0 + w*16 + g*4 + i]) * maxn + 1.0f;

  f32x4 acc_o[4] = {};
  float psum[4] = {0.f,0.f,0.f,0.f};

  for(int kt=0; kt<16; ++kt){
    if(kt < 15) issue(kt+1, (kt+1)&1);
    int pb = kt&1;

    // S = Q K^T (swizzled frag reads)
    f32x4 accs[4];
    __builtin_amdgcn_s_setprio(1);
#pragma unroll
    for(int nt=0; nt<4; ++nt){
      f32x4 z = {};
#pragma unroll
      for(int kc=0; kc<2; ++kc){
        short8 kb = *(const short8*)&Ks[pb][(nt*16+li)*64 + (((kc*4+g)^(li&7))*8)];
        z = __builtin_amdgcn_mfma_f32_16x16x32_bf16(qa[kc], kb, z, 0,0,0);
      }
      accs[nt] = z;
    }
    __builtin_amdgcn_s_setprio(0);
    int bkc[4];
#pragma unroll
    for(int nt=0;nt<4;++nt) bkc[nt] = bks[pb][nt*16 + li];

    // p = exp(logit - M_row); no max-tracking, no rescale
#pragma unroll
    for(int i=0;i<4;++i){
      int rloc = w*16 + g*4 + i;
      int bq = bqs[rloc];
      float rs = 0.f;
#pragma unroll
      for(int nt=0;nt<4;++nt){
        float cnt = (bkc[nt] == bq) ? 63.f : 62.f;
        float e = __expf(accs[nt][i] * (invsq * cnt) - Mrow[i]);
        rs += e;
        Ps[rloc*68 + nt*16 + li] = f2b(e);
      }
      psum[i] += rs;
    }
    // O += P @ V
    __builtin_amdgcn_s_setprio(1);
#pragma unroll
    for(int dt=0; dt<4; ++dt){
      f32x4 z = acc_o[dt];
#pragma unroll
      for(int kc=0; kc<2; ++kc){
        short8 pa = *(const short8*)&Ps[(w*16+li)*68 + kc*32 + g*8];
        short8 vb = *(const short8*)&Vs[pb][(dt*16+li)*64 + (((kc*4+g)^(li&7))*8)];
        z = __builtin_amdgcn_mfma_f32_16x16x32_bf16(pa, vb, z, 0,0,0);
      }
      acc_o[dt] = z;
    }
    __builtin_amdgcn_s_setprio(0);
    __syncthreads();
  }
  // one-time row-sum reduction across the 16 li lanes of each group
#pragma unroll
  for(int i=0;i<4;++i){
#pragma unroll
    for(int o=8;o;o>>=1) psum[i] += __shfl_xor(psum[i], o, 64);
  }
  float* obase = outp + ((size_t)(b*SEQ_ + q0 + w*16 + g*4))*E_ + h*DH_;
#pragma unroll
  for(int i=0;i<4;++i){
    float inv = 1.0f / fmaxf(psum[i], 1e-35f);
#pragma unroll
    for(int dt=0;dt<4;++dt)
      obase[(size_t)i*E_ + dt*16 + li] = acc_o[dt][i] * inv;
  }
}

// layernorm over E=512: one wave per row, float4 vectorized, no barriers
__global__ __launch_bounds__(256) void ln_kernel(
    const float* __restrict__ in, const float* __restrict__ g,
    const float* __restrict__ bb, float* __restrict__ outp,
    ushort* __restrict__ oh){
  int row = blockIdx.x*4 + (threadIdx.x>>6);
  int lane = threadIdx.x & 63;
  const float4* xr = (const float4*)(in + (size_t)row*E_);
  float4 v0 = xr[lane*2], v1 = xr[lane*2+1];
  float s  = v0.x+v0.y+v0.z+v0.w + v1.x+v1.y+v1.z+v1.w;
  float s2 = v0.x*v0.x+v0.y*v0.y+v0.z*v0.z+v0.w*v0.w
           + v1.x*v1.x+v1.y*v1.y+v1.z*v1.z+v1.w*v1.w;
#pragma unroll
  for(int o=32;o;o>>=1){ s += __shfl_xor(s,o,64); s2 += __shfl_xor(s2,o,64); }
  float mean = s*(1.0f/E_);
  float var  = s2*(1.0f/E_) - mean*mean;
  float inv = rsqrtf(var + 1e-5f);
  const float4* g4 = (const float4*)(g) + lane*2;
  const float4* b4 = (const float4*)(bb) + lane*2;
  float4 g0 = g4[0], g1 = g4[1], b0 = b4[0], b1 = b4[1];
  float4 y0, y1;
  y0.x=(v0.x-mean)*inv*g0.x+b0.x; y0.y=(v0.y-mean)*inv*g0.y+b0.y;
  y0.z=(v0.z-mean)*inv*g0.z+b0.z; y0.w=(v0.w-mean)*inv*g0.w+b0.w;
  y1.x=(v1.x-mean)*inv*g1.x+b1.x; y1.y=(v1.y-mean)*inv*g1.y+b1.y;
  y1.z=(v1.z-mean)*inv*g1.z+b1.z; y1.w=(v1.w-mean)*inv*g1.w+b1.w;
  float4* orow = (float4*)(outp + (size_t)row*E_) + lane*2;
  orow[0] = y0; orow[1] = y1;
  ushort hs[8];
  hs[0]=f2b(y0.x); hs[1]=f2b(y0.y); hs[2]=f2b(y0.z); hs[3]=f2b(y0.w);
  hs[4]=f2b(y1.x); hs[5]=f2b(y1.y); hs[6]=f2b(y1.z); hs[7]=f2b(y1.w);
  *(uint4*)&oh[(size_t)row*E_ + lane*8] = *(uint4*)hs;
}

// combine W2 K-split partials + bias + residual, then layernorm
__global__ __launch_bounds__(256) void ln2_kernel(
    const float* __restrict__ P, const float* __restrict__ b2,
    const float* __restrict__ Xres, const float* __restrict__ g,
    const float* __restrict__ bb, float* __restrict__ outp,
    ushort* __restrict__ oh){
  int row = blockIdx.x*4 + (threadIdx.x>>6);
  int lane = threadIdx.x & 63;
  const float4* p0 = (const float4*)(P + (size_t)row*E_) + lane*2;
  const float4* p1 = (const float4*)(P + (size_t)NTOK_*E_ + (size_t)row*E_) + lane*2;
  const float4* xr = (const float4*)(Xres + (size_t)row*E_) + lane*2;
  const float4* c4 = (const float4*)(b2) + lane*2;
  float4 v0 = p0[0], v1 = p0[1], u0 = p1[0], u1 = p1[1];
  float4 x0 = xr[0], x1 = xr[1], cb0 = c4[0], cb1 = c4[1];
  v0.x += u0.x + cb0.x + x0.x; v0.y += u0.y + cb0.y + x0.y;
  v0.z += u0.z + cb0.z + x0.z; v0.w += u0.w + cb0.w + x0.w;
  v1.x += u1.x + cb1.x + x1.x; v1.y += u1.y + cb1.y + x1.y;
  v1.z += u1.z + cb1.z + x1.z; v1.w += u1.w + cb1.w + x1.w;
  float s  = v0.x+v0.y+v0.z+v0.w + v1.x+v1.y+v1.z+v1.w;
  float s2 = v0.x*v0.x+v0.y*v0.y+v0.z*v0.z+v0.w*v0.w
           + v1.x*v1.x+v1.y*v1.y+v1.z*v1.z+v1.w*v1.w;
#pragma unroll
  for(int o=32;o;o>>=1){ s += __shfl_xor(s,o,64); s2 += __shfl_xor(s2,o,64); }
  float mean = s*(1.0f/E_);
  float var  = s2*(1.0f/E_) - mean*mean;
  float inv = rsqrtf(var + 1e-5f);
  const float4* g4 = (const float4*)(g) + lane*2;
  const float4* b4 = (const float4*)(bb) + lane*2;
  float4 g0 = g4[0], g1 = g4[1], b0 = b4[0], b1 = b4[1];
  float4 y0, y1;
  y0.x=(v0.x-mean)*inv*g0.x+b0.x; y0.y=(v0.y-mean)*inv*g0.y+b0.y;
  y0.z=(v0.z-mean)*inv*g0.z+b0.z; y0.w=(v0.w-mean)*inv*g0.w+b0.w;
  y1.x=(v1.x-mean)*inv*g1.x+b1.x; y1.y=(v1.y-mean)*inv*g1.y+b1.y;
  y1.z=(v1.z-mean)*inv*g1.z+b1.z; y1.w=(v1.w-mean)*inv*g1.w+b1.w;
  float4* orow = (float4*)(outp + (size_t)row*E_) + lane*2;
  orow[0] = y0; orow[1] = y1;
  ushort hs[8];
  hs[0]=f2b(y0.x); hs[1]=f2b(y0.y); hs[2]=f2b(y0.z); hs[3]=f2b(y0.w);
  hs[4]=f2b(y1.x); hs[5]=f2b(y1.y); hs[6]=f2b(y1.z); hs[7]=f2b(y1.w);
  *(uint4*)&oh[(size_t)row*E_ + lane*8] = *(uint4*)hs;
}

__global__ void final_partial(const float* __restrict__ x, const float* __restrict__ Wm,
                              float* __restrict__ part){
  int b  = blockIdx.x >> 7;
  int ch = blockIdx.x & 127;
  const float* xb = x + (size_t)b*SEQ_*E_;
  int k0 = ch*4096;
  float acc[NC_] = {};
  for(int k=k0+threadIdx.x; k<k0+4096; k+=256){
    float xv = xb[k];
    const float* wrow = Wm + (size_t)k*NC_;
#pragma unroll
    for(int c=0;c<NC_;++c) acc[c] += xv*wrow[c];
  }
#pragma unroll
  for(int c=0;c<NC_;++c) acc[c] = wave_rsum(acc[c]);
  __shared__ float r[4][NC_];
  int w = threadIdx.x>>6, lane = threadIdx.x&63;
  if(lane==0){
#pragma unroll
    for(int c=0;c<NC_;++c) r[w][c] = acc[c];
  }
  __syncthreads();
  if(threadIdx.x==0){
#pragma unroll
    for(int c=0;c<NC_;++c)
      part[(size_t)blockIdx.x*NC_ + c] = r[0][c]+r[1][c]+r[2][c]+r[3][c];
  }
}

__global__ void final_reduce(const float* __restrict__ part, const float* __restrict__ bm,
                             float* __restrict__ out){
  int t = threadIdx.x;
  if(t >= B_*NC_) return;
  int b = t / NC_, c = t % NC_;
  float s = bm[c];
  for(int i=0;i<128;++i) s += part[(size_t)(b*128+i)*NC_ + c];
  out[t] = s;
}

extern "C" void kernel_launch(void* const* d_in, const int* in_sizes, int n_in,
                              void* d_out, int out_size, void* d_ws, size_t ws_size,
                              hipStream_t stream){
  const int*   inp   = (const int*)d_in[0];
  const float* emb   = (const float*)d_in[1];
  const float* gamma = (const float*)d_in[2];
  const float* beta  = (const float*)d_in[3];
  const float* Wq    = (const float*)d_in[4];
  const float* bq    = (const float*)d_in[5];
  const float* Wv    = (const float*)d_in[6];
  const float* bv    = (const float*)d_in[7];
  const float* hyper = (const float*)d_in[8];
  const float* W1    = (const float*)d_in[9];
  const float* b1    = (const float*)d_in[10];
  const float* W2    = (const float*)d_in[11];
  const float* b2    = (const float*)d_in[12];
  const float* Wm    = (const float*)d_in[13];
  const float* bm    = (const float*)d_in[14];
  float* out = (float*)d_out;

  char* ws = (char*)d_ws;
  size_t off = 0;
  auto alloc = [&](size_t bytes)->void*{
    void* p = ws + off; off += (bytes + 255) & ~(size_t)255; return p;
  };
  const size_t NTOK = (size_t)B_*SEQ_;
  float*  X    = (float*)alloc(NTOK*E_*sizeof(float));
  float*  A    = (float*)alloc(NTOK*E_*sizeof(float));
  float*  Op   = (float*)alloc((size_t)2*NTOK*E_*sizeof(float));   // W2 partials
  ushort* Xh   = (ushort*)alloc(NTOK*E_*sizeof(ushort));
  ushort* Hh   = (ushort*)alloc(NTOK*HID_*sizeof(ushort));
  int*    Bk   = (int*)  alloc((size_t)BH_*SEQ_*sizeof(int));
  float*  Qn2  = (float*)alloc((size_t)BH_*SEQ_*sizeof(float));
  float*  Pp   = (float*)alloc((size_t)B_*128*NC_*sizeof(float));
  ushort* Qh   = (ushort*)alloc((size_t)BH_*SEQ_*DH_*sizeof(ushort));
  ushort* Vt   = (ushort*)alloc((size_t)BH_*DH_*SEQ_*sizeof(ushort));
  ushort* WcatT= (ushort*)alloc((size_t)NCAT_*E_*sizeof(ushort));
  ushort* W1T  = (ushort*)alloc((size_t)HID_*E_*sizeof(ushort));
  ushort* W2T  = (ushort*)alloc((size_t)E_*HID_*sizeof(ushort));
  float*  bcat = (float*)alloc(NCAT_*sizeof(float));
  (void)ws_size; (void)in_sizes; (void)n_in; (void)out_size;

  // one-time weight prep
  transpose_cast<<<dim3(E_/32,  E_/32),  256, 0, stream>>>(Wq, WcatT, E_, E_);
  transpose_cast<<<dim3(E_/32,  E_/32),  256, 0, stream>>>(Wv, WcatT + (size_t)512*E_, E_, E_);
  wproj_build<<<128, 256, 0, stream>>>(Wq, hyper, WcatT);
  transpose_cast<<<dim3(HID_/32,E_/32),  256, 0, stream>>>(W1, W1T, E_, HID_);
  transpose_cast<<<dim3(E_/32,  HID_/32),256, 0, stream>>>(W2, W2T, HID_, E_);
  bias_build<<<5, 256, 0, stream>>>(bq, bv, hyper, bcat);

  embed_pe_kernel<<<B_*SEQ_, 256, 0, stream>>>(inp, emb, X, Xh);

  dim3 gQV(NCAT_/64, (B_*SEQ_)/64);       // 17 x 64 = 1088 blocks
  dim3 gF1(HID_/128, (B_*SEQ_)/128);      // 16 x 32 = 512 blocks
  dim3 gF2(E_/64,    (B_*SEQ_)/64, 2);    //  8 x 64 x 2 = 1024 blocks (K-split)
  for(int l=0;l<ENC_;++l){
    gemm_mfma<64,64,5><<<gQV, 256, 0, stream>>>(Xh, WcatT, bcat, nullptr, Bk, Qh, Vt, Qn2, B_*SEQ_, NCAT_, E_);
    attn_mfma_kernel<<<BH_*16, 256, 0, stream>>>(Qh, Vt, Bk, Qn2, A);
    ln_kernel<<<B_*SEQ_/4, 256, 0, stream>>>(A, gamma, beta, X, Xh);
    gemm_mfma<128,128,1><<<gF1, 256, 0, stream>>>(Xh, W1T, b1, nullptr, Hh, nullptr, nullptr, nullptr, B_*SEQ_, HID_, E_);
    gemm_mfma<64,64,6><<<gF2, 256, 0, stream>>>(Hh, W2T, b2, nullptr, Op, nullptr, nullptr, nullptr, B_*SEQ_, E_, HID_);
    ln2_kernel<<<B_*SEQ_/4, 256, 0, stream>>>(Op, b2, X, gamma, beta, X, Xh);
  }
  final_partial<<<B_*128, 256, 0, stream>>>(X, Wm, Pp);
  final_reduce<<<1, 32, 0, stream>>>(Pp, bm, out);
}